// Round 12
// baseline (167.331 us; speedup 1.0000x reference)
//
#include <hip/hip_runtime.h>
#include <math.h>

namespace {

typedef __attribute__((ext_vector_type(8))) __fp16 f16x8;
typedef __attribute__((ext_vector_type(4))) float f32x4;

constexpr int IN_DIM = 128;
constexpr int EFF    = 130 * 16;   // W1 node stride (floats)
constexpr int NODES  = 255;
constexpr int TS     = 32;         // samples per block (2 MFMA N-tiles per wave)
constexpr int BLOCK  = 256;
constexpr int NC     = 10;

// ---- prep: W1[:, :128, :] -> MFMA fragment layout, fp16 (single product) ----
// frag element (n, t, lane l, j): W[k = t*32 + (l>>4)*8 + j][hid = l&15]
__global__ __launch_bounds__(256) void prep_w1(const float* __restrict__ W1,
                                               f16x8* __restrict__ wfrag) {
    __shared__ float xs[IN_DIM * 16];      // 8 KB: rows 0..127 of this node
    const int n = blockIdx.x, tid = threadIdx.x;
    const float4* src = (const float4*)(W1 + (size_t)n * EFF);
    ((float4*)xs)[tid]       = src[tid];
    ((float4*)xs)[tid + 256] = src[tid + 256];
    __syncthreads();
    const int l = tid & 63, t = tid >> 6;
    const int k0 = t * 32 + (l >> 4) * 8, hid = l & 15;
    f16x8 hv;
    #pragma unroll
    for (int j = 0; j < 8; ++j)
        hv[j] = (__fp16)xs[(k0 + j) * 16 + hid];   // RNE
    wfrag[(n * 4 + t) * 64 + l] = hv;
}

// ---- main fused tree kernel ----
// R12 = R10 body (TS=32, 30 KB LDS -> 4-5 blocks/CU) with the spill bug
// fixed: amdgpu_waves_per_eu(2) MIN-ONLY keeps the allocator budget at
// 512/2 = 256 unified (128 arch-VGPR cap, fits ~110 demand) while letting
// runtime occupancy rise to 4+ waves/SIMD. R10's (4,4) halved the budget
// -> 64-VGPR cap -> scratch spills + 30 ms thrash dispatch.
__global__ __launch_bounds__(BLOCK) __attribute__((amdgpu_waves_per_eu(2)))
void tree_mfma(
    const float* __restrict__ x, const float* __restrict__ path_prob,
    const float* __restrict__ W1, const float* __restrict__ b1,
    const float* __restrict__ w2, const float* __restrict__ b2,
    const float* __restrict__ leaf_logits,
    const f16x8* __restrict__ wfrag,
    float* __restrict__ out)
{
    __shared__ float pp[128][TS];          // 16 KB: path probs, depths 0..6 only
    // rotating score buffers: buf0 (d=0,3,6): 64 rows @0; buf1 (d=1,4): 16 @64; buf2 (d=2,5): 32 @80
    __shared__ float scbuf[112][TS];       // 14 KB (reused for out-reduction)

    const int tid  = threadIdx.x;
    const int wv   = tid >> 6, l = tid & 63;
    const int quad = l >> 4,   col = l & 15;
    const int lo32 = l & 31;
    const int s0   = blockIdx.x * TS;

    if (tid < TS) pp[0][tid] = path_prob[s0 + tid];

    // x fragments (fp16): B operand B[k = t*32+quad*8+j][col = sample&15]
    f16x8 xh[4][2];
    #pragma unroll
    for (int t = 0; t < 4; ++t)
        #pragma unroll
        for (int mt = 0; mt < 2; ++mt) {
            const float* xp = x + (size_t)(s0 + mt * 16 + col) * IN_DIM + t * 32 + quad * 8;
            float4 v0 = ((const float4*)xp)[0];
            float4 v1 = ((const float4*)xp)[1];
            float vv[8] = {v0.x, v0.y, v0.z, v0.w, v1.x, v1.y, v1.z, v1.w};
            f16x8 hv;
            #pragma unroll
            for (int j = 0; j < 8; ++j) hv[j] = (__fp16)vv[j];
            xh[t][mt] = hv;
        }
    // no barrier needed: first cross-wave LDS reads are behind the d0->d1 barrier

    const int wbase[3] = {0, 64, 80};

    // peel: preload first node's full W (per-wave first node: {0,2,5,6})
    const int first_n = (wv == 0) ? 0 : (wv == 1) ? 2 : (wv == 2) ? 5 : 6;
    f16x8 wcur[4];
    #pragma unroll
    for (int t = 0; t < 4; ++t) wcur[t] = wfrag[(size_t)first_n * 256 + t * 64 + l];

    // ---------------- depths 0..6 ----------------
    for (int d = 0; d < 7; ++d) {
        const int nd = 1 << d;
        float (*scW)[TS]  = (float(*)[TS])&scbuf[wbase[d % 3]][0];
        float (*scP)[TS]  = (float(*)[TS])&scbuf[wbase[(d + 2) % 3]][0];   // d-1
        float (*scP2)[TS] = (float(*)[TS])&scbuf[wbase[(d + 1) % 3]][0];   // d-2
        const int stride = 128 >> d, half = 64 >> d;

        for (int nl = wv; nl < nd; nl += 4) {
            const int n = nd - 1 + nl;
            // successor node in this wave's global sequence (crosses depth bound)
            const int nn = (nl + 4 < nd) ? (n + 4) : (2 * nd - 1 + wv);

            // ---- full next-node W prefetch: consumed NEXT iteration ----
            f16x8 wnext[4];
            {
                const f16x8* wnp = wfrag + (size_t)nn * 256 + l;
                #pragma unroll
                for (int t = 0; t < 4; ++t) wnext[t] = wnp[t * 64];
            }

            // ---- hoisted epilogue operands ----
            const float4 b1q = ((const float4*)(b1 + n * 16))[quad];
            const float4 w2q = ((const float4*)(w2 + n * 16))[quad];
            const float4 wpq = ((const float4*)(W1 + (size_t)n * EFF + 128 * 16))[quad];
            const float4 wgq = ((const float4*)(W1 + (size_t)n * EFF + 129 * 16))[quad];
            const float  b2v = b2[n];
            const int    slot = nl * stride;
            const float  ppar = pp[slot][lo32];
            float par[2], gp[2];
            #pragma unroll
            for (int mt = 0; mt < 2; ++mt) {
                const int scol = mt * 16 + col;
                par[mt] = (d >= 1) ? scP[nl >> 1][scol] : 0.0f;
                gp[mt]  = (d >= 2) ? scP2[nl >> 2][scol] : 0.0f;
            }

            // ---- MFMA t-loop: all operands already resident ----
            f32x4 binit = {b1q.x, b1q.y, b1q.z, b1q.w};
            f32x4 acc[2] = {binit, binit};
            #pragma unroll
            for (int t = 0; t < 4; ++t) {
                acc[0] = __builtin_amdgcn_mfma_f32_16x16x32_f16(wcur[t], xh[t][0], acc[0], 0, 0, 0);
                acc[1] = __builtin_amdgcn_mfma_f32_16x16x32_f16(wcur[t], xh[t][1], acc[1], 0, 0, 0);
            }

            // epilogue: D[hid=quad*4+r][s=mt*16+col]; hid-reduce = 3 adds + 2 shfls
            float score01[2];
            #pragma unroll
            for (int mt = 0; mt < 2; ++mt) {
                const f32x4 a = acc[mt];
                const float pa = par[mt], ga = gp[mt];
                float ts = 0.0f;
                #pragma unroll
                for (int r = 0; r < 4; ++r) {
                    const float wpr = (r == 0) ? wpq.x : (r == 1) ? wpq.y : (r == 2) ? wpq.z : wpq.w;
                    const float wgr = (r == 0) ? wgq.x : (r == 1) ? wgq.y : (r == 2) ? wgq.z : wgq.w;
                    const float w2r = (r == 0) ? w2q.x : (r == 1) ? w2q.y : (r == 2) ? w2q.z : w2q.w;
                    const float h = fmaf(pa, wpr, fmaf(ga, wgr, a[r]));
                    ts = fmaf(fmaxf(h, 0.0f), w2r, ts);
                }
                ts += __shfl_xor(ts, 16);
                ts += __shfl_xor(ts, 32);
                score01[mt] = ts;
            }
            // sample lo32 owned by lane lo32 (half-waves hold identical reductions)
            const float sv = ((l & 16) ? score01[1] : score01[0]) + b2v;

            if (l < 32) {
                scW[nl][lo32] = sv;
                const float p = 1.0f / (1.0f + __expf(-sv));
                pp[slot][lo32]        = ppar * p;
                pp[slot + half][lo32] = ppar * (1.0f - p);
            }

            #pragma unroll
            for (int t = 0; t < 4; ++t) wcur[t] = wnext[t];
        }
        __syncthreads();
    }

    // ---------------- depth 7: fold leaf mixture, accumulate in VGPRs ----------------
    float oacc[NC];
    #pragma unroll
    for (int c = 0; c < NC; ++c) oacc[c] = 0.0f;
    {
        float (*scP)[TS]  = (float(*)[TS])&scbuf[wbase[0]][0];   // d=6 scores
        float (*scP2)[TS] = (float(*)[TS])&scbuf[wbase[2]][0];   // d=5 scores

        for (int nl = wv; nl < 128; nl += 4) {
            const int n = 127 + nl;
            const int nn = (nl + 4 < 128) ? (n + 4) : 254;   // dummy refetch at end

            f16x8 wnext[4];
            {
                const f16x8* wnp = wfrag + (size_t)nn * 256 + l;
                #pragma unroll
                for (int t = 0; t < 4; ++t) wnext[t] = wnp[t * 64];
            }

            const float4 b1q = ((const float4*)(b1 + n * 16))[quad];
            const float4 w2q = ((const float4*)(w2 + n * 16))[quad];
            const float4 wpq = ((const float4*)(W1 + (size_t)n * EFF + 128 * 16))[quad];
            const float4 wgq = ((const float4*)(W1 + (size_t)n * EFF + 129 * 16))[quad];
            const float  b2v = b2[n];
            const float  ppar = pp[nl][lo32];
            float par[2], gp[2];
            #pragma unroll
            for (int mt = 0; mt < 2; ++mt) {
                const int scol = mt * 16 + col;
                par[mt] = scP[nl >> 1][scol];
                gp[mt]  = scP2[nl >> 2][scol];
            }

            f32x4 binit = {b1q.x, b1q.y, b1q.z, b1q.w};
            f32x4 acc[2] = {binit, binit};
            #pragma unroll
            for (int t = 0; t < 4; ++t) {
                acc[0] = __builtin_amdgcn_mfma_f32_16x16x32_f16(wcur[t], xh[t][0], acc[0], 0, 0, 0);
                acc[1] = __builtin_amdgcn_mfma_f32_16x16x32_f16(wcur[t], xh[t][1], acc[1], 0, 0, 0);
            }

            float score01[2];
            #pragma unroll
            for (int mt = 0; mt < 2; ++mt) {
                const f32x4 a = acc[mt];
                const float pa = par[mt], ga = gp[mt];
                float ts = 0.0f;
                #pragma unroll
                for (int r = 0; r < 4; ++r) {
                    const float wpr = (r == 0) ? wpq.x : (r == 1) ? wpq.y : (r == 2) ? wpq.z : wpq.w;
                    const float wgr = (r == 0) ? wgq.x : (r == 1) ? wgq.y : (r == 2) ? wgq.z : wgq.w;
                    const float w2r = (r == 0) ? w2q.x : (r == 1) ? w2q.y : (r == 2) ? w2q.z : w2q.w;
                    const float h = fmaf(pa, wpr, fmaf(ga, wgr, a[r]));
                    ts = fmaf(fmaxf(h, 0.0f), w2r, ts);
                }
                ts += __shfl_xor(ts, 16);
                ts += __shfl_xor(ts, 32);
                score01[mt] = ts;
            }
            const float sv = ((l & 16) ? score01[1] : score01[0]) + b2v;

            const float p = 1.0f / (1.0f + __expf(-sv));
            const float pL = ppar * p;
            const float pR = ppar * (1.0f - p);
            const float* llp = leaf_logits + (size_t)(2 * nl) * NC;
            #pragma unroll
            for (int c = 0; c < NC; ++c)
                oacc[c] = fmaf(pL, llp[c], fmaf(pR, llp[NC + c], oacc[c]));

            #pragma unroll
            for (int t = 0; t < 4; ++t) wcur[t] = wnext[t];
        }
    }

    // ---------------- cross-wave out reduction through scbuf ----------------
    __syncthreads();
    {
        float* red = &scbuf[0][0];         // 4*32*10 = 1280 floats <= 3584
        if (l < 32) {
            #pragma unroll
            for (int c = 0; c < NC; ++c)
                red[(wv * 32 + lo32) * NC + c] = oacc[c];
        }
    }
    __syncthreads();
    {
        const float* red = &scbuf[0][0];
        for (int i = tid; i < TS * NC; i += BLOCK) {
            float v = red[i] + red[320 + i] + red[640 + i] + red[960 + i];
            out[(size_t)s0 * NC + i] = v;
        }
    }
}

} // namespace

extern "C" void kernel_launch(void* const* d_in, const int* in_sizes, int n_in,
                              void* d_out, int out_size, void* d_ws, size_t ws_size,
                              hipStream_t stream) {
    const float* x           = (const float*)d_in[0];
    const float* path_prob   = (const float*)d_in[1];
    const float* W1          = (const float*)d_in[2];
    const float* b1          = (const float*)d_in[3];
    const float* w2          = (const float*)d_in[4];
    const float* b2          = (const float*)d_in[5];
    const float* leaf_logits = (const float*)d_in[6];
    float* out = (float*)d_out;

    const int batch = in_sizes[0] / IN_DIM;                // 32768
    f16x8* wfrag = (f16x8*)d_ws;                           // 255*4*64*16B ~= 1.04 MB

    hipLaunchKernelGGL(prep_w1, dim3(NODES), dim3(256), 0, stream, W1, wfrag);
    hipLaunchKernelGGL(tree_mfma, dim3(batch / TS), dim3(BLOCK), 0, stream,
                       x, path_prob, W1, b1, w2, b2, leaf_logits, wfrag, out);
}

// Round 13
// 144.304 us; speedup vs baseline: 1.1596x; 1.1596x over previous
//
#include <hip/hip_runtime.h>
#include <math.h>

namespace {

typedef __attribute__((ext_vector_type(8))) __fp16 f16x8;
typedef __attribute__((ext_vector_type(4))) float f32x4;

constexpr int IN_DIM = 128;
constexpr int EFF    = 130 * 16;   // W1 node stride (floats)
constexpr int NODES  = 255;
constexpr int TS     = 64;         // samples per block (4 MFMA N-tiles per wave)
constexpr int BLOCK  = 256;
constexpr int NC     = 10;

// ---- prep: W1[:, :128, :] -> MFMA fragment layout, fp16 (single product) ----
// frag element (n, t, lane l, j): W[k = t*32 + (l>>4)*8 + j][hid = l&15]
__global__ __launch_bounds__(256) void prep_w1(const float* __restrict__ W1,
                                               f16x8* __restrict__ wfrag) {
    __shared__ float xs[IN_DIM * 16];      // 8 KB: rows 0..127 of this node
    const int n = blockIdx.x, tid = threadIdx.x;
    const float4* src = (const float4*)(W1 + (size_t)n * EFF);
    ((float4*)xs)[tid]       = src[tid];
    ((float4*)xs)[tid + 256] = src[tid + 256];
    __syncthreads();
    const int l = tid & 63, t = tid >> 6;
    const int k0 = t * 32 + (l >> 4) * 8, hid = l & 15;
    f16x8 hv;
    #pragma unroll
    for (int j = 0; j < 8; ++j)
        hv[j] = (__fp16)xs[(k0 + j) * 16 + hid];   // RNE
    wfrag[(n * 4 + t) * 64 + l] = hv;
}

__device__ __forceinline__ void loadW(const f16x8* __restrict__ wfrag, int n, int l,
                                      f16x8 (&w)[4]) {
    const f16x8* wp = wfrag + (size_t)n * 256 + l;
    #pragma unroll
    for (int t = 0; t < 4; ++t) w[t] = wp[t * 64];
}

__device__ __forceinline__ void mfma16(const f16x8 (&w)[4], const f16x8 (&xh)[4][4],
                                       f32x4 (&acc)[4]) {
    #pragma unroll
    for (int t = 0; t < 4; ++t)
        #pragma unroll
        for (int mt = 0; mt < 4; ++mt)
            acc[mt] = __builtin_amdgcn_mfma_f32_16x16x32_f16(w[t], xh[t][mt], acc[mt], 0, 0, 0);
}

// combine + hid-reduce (3 in-lane adds + 2 shfls per mt) + lane-select
__device__ __forceinline__ float epilogue_score(
    const f32x4 (&acc)[4], const float4& w2q, const float4& wpq, const float4& wgq,
    const float (&par)[4], const float (&gp)[4], float b2v, int quad)
{
    float score01[4];
    #pragma unroll
    for (int mt = 0; mt < 4; ++mt) {
        float ts = 0.0f;
        #pragma unroll
        for (int r = 0; r < 4; ++r) {
            const float wpr = (r == 0) ? wpq.x : (r == 1) ? wpq.y : (r == 2) ? wpq.z : wpq.w;
            const float wgr = (r == 0) ? wgq.x : (r == 1) ? wgq.y : (r == 2) ? wgq.z : wgq.w;
            const float w2r = (r == 0) ? w2q.x : (r == 1) ? w2q.y : (r == 2) ? w2q.z : w2q.w;
            const float h = fmaf(par[mt], wpr, fmaf(gp[mt], wgr, acc[mt][r]));
            ts = fmaf(fmaxf(h, 0.0f), w2r, ts);
        }
        ts += __shfl_xor(ts, 16);
        ts += __shfl_xor(ts, 32);
        score01[mt] = ts;
    }
    const float sa = (quad & 1) ? score01[1] : score01[0];
    const float sb = (quad & 1) ? score01[3] : score01[2];
    return ((quad & 2) ? sb : sa) + b2v;
}

// ---- main fused tree kernel ----
// R13: 2-node ILP pairing for d>=3 (62/65 node-visits): both nodes' W loads
// issued together, 32 MFMAs, two INDEPENDENT epilogue chains interleaved by
// the scheduler -> exposed serial latency per node ~halves, iterations 65->35.
// wnext rotation dropped (measured neutral in R11) to pay the register bill.
__global__ __launch_bounds__(BLOCK) __attribute__((amdgpu_waves_per_eu(2, 2)))
void tree_mfma(
    const float* __restrict__ x, const float* __restrict__ path_prob,
    const float* __restrict__ W1, const float* __restrict__ b1,
    const float* __restrict__ w2, const float* __restrict__ b2,
    const float* __restrict__ leaf_logits,
    const f16x8* __restrict__ wfrag,
    float* __restrict__ out)
{
    __shared__ float pp[128][TS];          // 32 KB: path probs, depths 0..6 only
    // rotating score buffers: buf0 (d=0,3,6): 64 rows @0; buf1 (d=1,4): 16 @64; buf2 (d=2,5): 32 @80
    __shared__ float scbuf[112][TS];       // 28 KB (reused for out-reduction)

    const int tid  = threadIdx.x;
    const int wv   = tid >> 6, l = tid & 63;
    const int quad = l >> 4,   col = l & 15;
    const int s0   = blockIdx.x * TS;

    if (tid < TS) pp[0][tid] = path_prob[s0 + tid];

    // x fragments (fp16): B operand B[k = t*32+quad*8+j][col]
    f16x8 xh[4][4];
    #pragma unroll
    for (int t = 0; t < 4; ++t)
        #pragma unroll
        for (int mt = 0; mt < 4; ++mt) {
            const float* xp = x + (size_t)(s0 + mt * 16 + col) * IN_DIM + t * 32 + quad * 8;
            float4 v0 = ((const float4*)xp)[0];
            float4 v1 = ((const float4*)xp)[1];
            float vv[8] = {v0.x, v0.y, v0.z, v0.w, v1.x, v1.y, v1.z, v1.w};
            f16x8 hv;
            #pragma unroll
            for (int j = 0; j < 8; ++j) hv[j] = (__fp16)vv[j];
            xh[t][mt] = hv;
        }

    const int wbase[3] = {0, 64, 80};

    // ---------------- depths 0..2: single node per wave ----------------
    for (int d = 0; d < 3; ++d) {
        const int nd = 1 << d;
        float (*scW)[TS]  = (float(*)[TS])&scbuf[wbase[d % 3]][0];
        float (*scP)[TS]  = (float(*)[TS])&scbuf[wbase[(d + 2) % 3]][0];
        float (*scP2)[TS] = (float(*)[TS])&scbuf[wbase[(d + 1) % 3]][0];
        const int stride = 128 >> d, half = 64 >> d;

        for (int nl = wv; nl < nd; nl += 4) {
            const int n = nd - 1 + nl;
            f16x8 w[4];
            loadW(wfrag, n, l, w);
            const float4 b1q = ((const float4*)(b1 + n * 16))[quad];
            const float4 w2q = ((const float4*)(w2 + n * 16))[quad];
            const float4 wpq = ((const float4*)(W1 + (size_t)n * EFF + 128 * 16))[quad];
            const float4 wgq = ((const float4*)(W1 + (size_t)n * EFF + 129 * 16))[quad];
            const float  b2v = b2[n];
            const int    slot = nl * stride;
            const float  ppar = pp[slot][l];
            float par[4], gp[4];
            #pragma unroll
            for (int mt = 0; mt < 4; ++mt) {
                const int scol = mt * 16 + col;
                par[mt] = (d >= 1) ? scP[nl >> 1][scol] : 0.0f;
                gp[mt]  = (d >= 2) ? scP2[nl >> 2][scol] : 0.0f;
            }
            f32x4 binit = {b1q.x, b1q.y, b1q.z, b1q.w};
            f32x4 acc[4] = {binit, binit, binit, binit};
            mfma16(w, xh, acc);
            const float sv = epilogue_score(acc, w2q, wpq, wgq, par, gp, b2v, quad);
            scW[nl][l] = sv;
            const float p = 1.0f / (1.0f + __expf(-sv));
            pp[slot][l]        = ppar * p;
            pp[slot + half][l] = ppar * (1.0f - p);
        }
        __syncthreads();
    }

    // ---------------- depths 3..6: paired nodes (nl, nl+4) ----------------
    for (int d = 3; d < 7; ++d) {
        const int nd = 1 << d;
        float (*scW)[TS]  = (float(*)[TS])&scbuf[wbase[d % 3]][0];
        float (*scP)[TS]  = (float(*)[TS])&scbuf[wbase[(d + 2) % 3]][0];
        float (*scP2)[TS] = (float(*)[TS])&scbuf[wbase[(d + 1) % 3]][0];
        const int stride = 128 >> d, half = 64 >> d;

        for (int nl = wv; nl < nd; nl += 8) {
            const int nA = nd - 1 + nl, nB = nA + 4;

            f16x8 wA[4], wB[4];
            loadW(wfrag, nA, l, wA);
            loadW(wfrag, nB, l, wB);

            const float4 b1qA = ((const float4*)(b1 + nA * 16))[quad];
            const float4 b1qB = ((const float4*)(b1 + nB * 16))[quad];
            const float4 w2qA = ((const float4*)(w2 + nA * 16))[quad];
            const float4 w2qB = ((const float4*)(w2 + nB * 16))[quad];
            const float4 wpqA = ((const float4*)(W1 + (size_t)nA * EFF + 128 * 16))[quad];
            const float4 wpqB = ((const float4*)(W1 + (size_t)nB * EFF + 128 * 16))[quad];
            const float4 wgqA = ((const float4*)(W1 + (size_t)nA * EFF + 129 * 16))[quad];
            const float4 wgqB = ((const float4*)(W1 + (size_t)nB * EFF + 129 * 16))[quad];
            const float  b2vA = b2[nA], b2vB = b2[nB];
            const int    slotA = nl * stride, slotB = (nl + 4) * stride;
            const float  pparA = pp[slotA][l], pparB = pp[slotB][l];
            float parA[4], gpA[4], parB[4], gpB[4];
            #pragma unroll
            for (int mt = 0; mt < 4; ++mt) {
                const int scol = mt * 16 + col;
                parA[mt] = scP[nl >> 1][scol];
                gpA[mt]  = scP2[nl >> 2][scol];
                parB[mt] = scP[(nl + 4) >> 1][scol];
                gpB[mt]  = scP2[(nl + 4) >> 2][scol];
            }

            f32x4 binitA = {b1qA.x, b1qA.y, b1qA.z, b1qA.w};
            f32x4 binitB = {b1qB.x, b1qB.y, b1qB.z, b1qB.w};
            f32x4 accA[4] = {binitA, binitA, binitA, binitA};
            f32x4 accB[4] = {binitB, binitB, binitB, binitB};
            mfma16(wA, xh, accA);
            mfma16(wB, xh, accB);

            // two independent epilogue chains -> scheduler interleaves
            const float svA = epilogue_score(accA, w2qA, wpqA, wgqA, parA, gpA, b2vA, quad);
            const float svB = epilogue_score(accB, w2qB, wpqB, wgqB, parB, gpB, b2vB, quad);

            scW[nl][l]     = svA;
            scW[nl + 4][l] = svB;
            const float pA = 1.0f / (1.0f + __expf(-svA));
            const float pB = 1.0f / (1.0f + __expf(-svB));
            pp[slotA][l]        = pparA * pA;
            pp[slotA + half][l] = pparA * (1.0f - pA);
            pp[slotB][l]        = pparB * pB;
            pp[slotB + half][l] = pparB * (1.0f - pB);
        }
        __syncthreads();
    }

    // ---------------- depth 7: paired, fold leaf mixture into VGPRs ----------------
    float oacc[NC];
    #pragma unroll
    for (int c = 0; c < NC; ++c) oacc[c] = 0.0f;
    {
        float (*scP)[TS]  = (float(*)[TS])&scbuf[wbase[0]][0];   // d=6 scores
        float (*scP2)[TS] = (float(*)[TS])&scbuf[wbase[2]][0];   // d=5 scores

        for (int nl = wv; nl < 128; nl += 8) {
            const int nA = 127 + nl, nB = nA + 4;

            f16x8 wA[4], wB[4];
            loadW(wfrag, nA, l, wA);
            loadW(wfrag, nB, l, wB);

            const float4 b1qA = ((const float4*)(b1 + nA * 16))[quad];
            const float4 b1qB = ((const float4*)(b1 + nB * 16))[quad];
            const float4 w2qA = ((const float4*)(w2 + nA * 16))[quad];
            const float4 w2qB = ((const float4*)(w2 + nB * 16))[quad];
            const float4 wpqA = ((const float4*)(W1 + (size_t)nA * EFF + 128 * 16))[quad];
            const float4 wpqB = ((const float4*)(W1 + (size_t)nB * EFF + 128 * 16))[quad];
            const float4 wgqA = ((const float4*)(W1 + (size_t)nA * EFF + 129 * 16))[quad];
            const float4 wgqB = ((const float4*)(W1 + (size_t)nB * EFF + 129 * 16))[quad];
            const float  b2vA = b2[nA], b2vB = b2[nB];
            const float  pparA = pp[nl][l], pparB = pp[nl + 4][l];
            float parA[4], gpA[4], parB[4], gpB[4];
            #pragma unroll
            for (int mt = 0; mt < 4; ++mt) {
                const int scol = mt * 16 + col;
                parA[mt] = scP[nl >> 1][scol];
                gpA[mt]  = scP2[nl >> 2][scol];
                parB[mt] = scP[(nl + 4) >> 1][scol];
                gpB[mt]  = scP2[(nl + 4) >> 2][scol];
            }

            f32x4 binitA = {b1qA.x, b1qA.y, b1qA.z, b1qA.w};
            f32x4 binitB = {b1qB.x, b1qB.y, b1qB.z, b1qB.w};
            f32x4 accA[4] = {binitA, binitA, binitA, binitA};
            f32x4 accB[4] = {binitB, binitB, binitB, binitB};
            mfma16(wA, xh, accA);
            mfma16(wB, xh, accB);

            const float svA = epilogue_score(accA, w2qA, wpqA, wgqA, parA, gpA, b2vA, quad);
            const float svB = epilogue_score(accB, w2qB, wpqB, wgqB, parB, gpB, b2vB, quad);

            const float pA = 1.0f / (1.0f + __expf(-svA));
            const float pB = 1.0f / (1.0f + __expf(-svB));
            const float pLA = pparA * pA, pRA = pparA * (1.0f - pA);
            const float pLB = pparB * pB, pRB = pparB * (1.0f - pB);
            const float* llpA = leaf_logits + (size_t)(2 * nl) * NC;
            const float* llpB = leaf_logits + (size_t)(2 * (nl + 4)) * NC;
            #pragma unroll
            for (int c = 0; c < NC; ++c) {
                float v = fmaf(pLA, llpA[c], fmaf(pRA, llpA[NC + c], oacc[c]));
                oacc[c] = fmaf(pLB, llpB[c], fmaf(pRB, llpB[NC + c], v));
            }
        }
    }

    // ---------------- cross-wave out reduction through scbuf ----------------
    __syncthreads();
    {
        float* red = &scbuf[0][0];         // 4*64*10 = 2560 floats <= 7168
        #pragma unroll
        for (int c = 0; c < NC; ++c)
            red[(wv * 64 + l) * NC + c] = oacc[c];
    }
    __syncthreads();
    {
        const float* red = &scbuf[0][0];
        for (int i = tid; i < TS * NC; i += BLOCK) {
            float v = red[i] + red[640 + i] + red[1280 + i] + red[1920 + i];
            out[(size_t)s0 * NC + i] = v;
        }
    }
}

} // namespace

extern "C" void kernel_launch(void* const* d_in, const int* in_sizes, int n_in,
                              void* d_out, int out_size, void* d_ws, size_t ws_size,
                              hipStream_t stream) {
    const float* x           = (const float*)d_in[0];
    const float* path_prob   = (const float*)d_in[1];
    const float* W1          = (const float*)d_in[2];
    const float* b1          = (const float*)d_in[3];
    const float* w2          = (const float*)d_in[4];
    const float* b2          = (const float*)d_in[5];
    const float* leaf_logits = (const float*)d_in[6];
    float* out = (float*)d_out;

    const int batch = in_sizes[0] / IN_DIM;                // 32768
    f16x8* wfrag = (f16x8*)d_ws;                           // 255*4*64*16B ~= 1.04 MB

    hipLaunchKernelGGL(prep_w1, dim3(NODES), dim3(256), 0, stream, W1, wfrag);
    hipLaunchKernelGGL(tree_mfma, dim3(batch / TS), dim3(BLOCK), 0, stream,
                       x, path_prob, W1, b1, w2, b2, leaf_logits, wfrag, out);
}

// Round 14
// 140.094 us; speedup vs baseline: 1.1944x; 1.0300x over previous
//
#include <hip/hip_runtime.h>
#include <math.h>

namespace {

typedef __attribute__((ext_vector_type(8))) __fp16 f16x8;
typedef __attribute__((ext_vector_type(4))) float f32x4;

constexpr int IN_DIM = 128;
constexpr int EFF    = 130 * 16;   // W1 node stride (floats)
constexpr int NODES  = 255;
constexpr int TS     = 64;         // samples per block (4 MFMA N-tiles per wave)
constexpr int BLOCK  = 256;
constexpr int NC     = 10;

// ---- prep: W1[:, :128, :] -> MFMA fragment layout, fp16 (single product) ----
// frag element (n, t, lane l, j): W[k = t*32 + (l>>4)*8 + j][hid = l&15]
__global__ __launch_bounds__(256) void prep_w1(const float* __restrict__ W1,
                                               f16x8* __restrict__ wfrag) {
    __shared__ float xs[IN_DIM * 16];      // 8 KB: rows 0..127 of this node
    const int n = blockIdx.x, tid = threadIdx.x;
    const float4* src = (const float4*)(W1 + (size_t)n * EFF);
    ((float4*)xs)[tid]       = src[tid];
    ((float4*)xs)[tid + 256] = src[tid + 256];
    __syncthreads();
    const int l = tid & 63, t = tid >> 6;
    const int k0 = t * 32 + (l >> 4) * 8, hid = l & 15;
    f16x8 hv;
    #pragma unroll
    for (int j = 0; j < 8; ++j)
        hv[j] = (__fp16)xs[(k0 + j) * 16 + hid];   // RNE
    wfrag[(n * 4 + t) * 64 + l] = hv;
}

__device__ __forceinline__ void loadW(const f16x8* __restrict__ wfrag, int n, int l,
                                      f16x8 (&w)[4]) {
    const f16x8* wp = wfrag + (size_t)n * 256 + l;
    #pragma unroll
    for (int t = 0; t < 4; ++t) w[t] = wp[t * 64];
}

__device__ __forceinline__ void mfma16(const f16x8 (&w)[4], const f16x8 (&xh)[4][4],
                                       f32x4 (&acc)[4]) {
    #pragma unroll
    for (int t = 0; t < 4; ++t)
        #pragma unroll
        for (int mt = 0; mt < 4; ++mt)
            acc[mt] = __builtin_amdgcn_mfma_f32_16x16x32_f16(w[t], xh[t][mt], acc[mt], 0, 0, 0);
}

// combine + hid-reduce (3 in-lane adds + 2 shfls per mt) + lane-select
__device__ __forceinline__ float epilogue_score(
    const f32x4 (&acc)[4], const float4& w2q, const float4& wpq, const float4& wgq,
    const float (&par)[4], const float (&gp)[4], float b2v, int quad)
{
    float score01[4];
    #pragma unroll
    for (int mt = 0; mt < 4; ++mt) {
        float ts = 0.0f;
        #pragma unroll
        for (int r = 0; r < 4; ++r) {
            const float wpr = (r == 0) ? wpq.x : (r == 1) ? wpq.y : (r == 2) ? wpq.z : wpq.w;
            const float wgr = (r == 0) ? wgq.x : (r == 1) ? wgq.y : (r == 2) ? wgq.z : wgq.w;
            const float w2r = (r == 0) ? w2q.x : (r == 1) ? w2q.y : (r == 2) ? w2q.z : w2q.w;
            const float h = fmaf(par[mt], wpr, fmaf(gp[mt], wgr, acc[mt][r]));
            ts = fmaf(fmaxf(h, 0.0f), w2r, ts);
        }
        ts += __shfl_xor(ts, 16);
        ts += __shfl_xor(ts, 32);
        score01[mt] = ts;
    }
    const float sa = (quad & 1) ? score01[1] : score01[0];
    const float sb = (quad & 1) ? score01[3] : score01[2];
    return ((quad & 2) ? sb : sa) + b2v;
}

// ---- main fused tree kernel ----
// R14: cross-iteration software pipeline. Each iter: (1) issue node-k W+b1
// loads; (2) run node-(k-1)'s epilogue (VALU/shfl hides the W L2 latency);
// (3) load node-k epilogue scalars (consumed next iter); (4) MFMA(k) into a
// rotating accumulator. Per-depth drain; arithmetic identical to R13.
__global__ __launch_bounds__(BLOCK) __attribute__((amdgpu_waves_per_eu(2, 2)))
void tree_mfma(
    const float* __restrict__ x, const float* __restrict__ path_prob,
    const float* __restrict__ W1, const float* __restrict__ b1,
    const float* __restrict__ w2, const float* __restrict__ b2,
    const float* __restrict__ leaf_logits,
    const f16x8* __restrict__ wfrag,
    float* __restrict__ out)
{
    __shared__ float pp[128][TS];          // 32 KB: path probs, depths 0..6 only
    // rotating score buffers: buf0 (d=0,3,6): 64 rows @0; buf1 (d=1,4): 16 @64; buf2 (d=2,5): 32 @80
    __shared__ float scbuf[112][TS];       // 28 KB (reused for out-reduction)

    const int tid  = threadIdx.x;
    const int wv   = tid >> 6, l = tid & 63;
    const int quad = l >> 4,   col = l & 15;
    const int s0   = blockIdx.x * TS;

    if (tid < TS) pp[0][tid] = path_prob[s0 + tid];

    // x fragments (fp16): B operand B[k = t*32+quad*8+j][col]
    f16x8 xh[4][4];
    #pragma unroll
    for (int t = 0; t < 4; ++t)
        #pragma unroll
        for (int mt = 0; mt < 4; ++mt) {
            const float* xp = x + (size_t)(s0 + mt * 16 + col) * IN_DIM + t * 32 + quad * 8;
            float4 v0 = ((const float4*)xp)[0];
            float4 v1 = ((const float4*)xp)[1];
            float vv[8] = {v0.x, v0.y, v0.z, v0.w, v1.x, v1.y, v1.z, v1.w};
            f16x8 hv;
            #pragma unroll
            for (int j = 0; j < 8; ++j) hv[j] = (__fp16)vv[j];
            xh[t][mt] = hv;
        }

    const int wbase[3] = {0, 64, 80};

    // ---------------- depths 0..6: software-pipelined node loop ----------------
    for (int d = 0; d < 7; ++d) {
        const int nd = 1 << d;
        float (*scW)[TS]  = (float(*)[TS])&scbuf[wbase[d % 3]][0];
        float (*scP)[TS]  = (float(*)[TS])&scbuf[wbase[(d + 2) % 3]][0];   // d-1
        float (*scP2)[TS] = (float(*)[TS])&scbuf[wbase[(d + 1) % 3]][0];   // d-2
        const int stride = 128 >> d, half = 64 >> d;

        bool havePrev = false;
        f32x4 accP[4];
        float4 p_w2q, p_wpq, p_wgq;
        float  p_b2v = 0.f, p_ppar = 0.f;
        float  p_par[4], p_gp[4];
        int    p_slot = 0, p_nl = 0;

        for (int nl = wv; nl < nd; nl += 4) {
            const int n = nd - 1 + nl;

            // (1) issue this node's W + b1 loads (latency hidden under prev epilogue)
            f16x8 w[4];
            loadW(wfrag, n, l, w);
            const float4 b1q = ((const float4*)(b1 + n * 16))[quad];

            // (2) overlapped epilogue of previous node (pure VALU/shfl/LDS)
            if (havePrev) {
                const float sv = epilogue_score(accP, p_w2q, p_wpq, p_wgq, p_par, p_gp, p_b2v, quad);
                scW[p_nl][l] = sv;
                const float p = 1.0f / (1.0f + __expf(-sv));
                pp[p_slot][l]        = p_ppar * p;
                pp[p_slot + half][l] = p_ppar * (1.0f - p);
            }

            // (3) this node's epilogue scalars (consumed NEXT iteration)
            const float4 w2q = ((const float4*)(w2 + n * 16))[quad];
            const float4 wpq = ((const float4*)(W1 + (size_t)n * EFF + 128 * 16))[quad];
            const float4 wgq = ((const float4*)(W1 + (size_t)n * EFF + 129 * 16))[quad];
            const float  b2v = b2[n];
            const int    slot = nl * stride;
            const float  ppar = pp[slot][l];
            float par[4], gp[4];
            #pragma unroll
            for (int mt = 0; mt < 4; ++mt) {
                const int scol = mt * 16 + col;
                par[mt] = (d >= 1) ? scP[nl >> 1][scol] : 0.0f;
                gp[mt]  = (d >= 2) ? scP2[nl >> 2][scol] : 0.0f;
            }

            // (4) MFMA into fresh accumulator (bias folded into init)
            f32x4 binit = {b1q.x, b1q.y, b1q.z, b1q.w};
            f32x4 acc[4] = {binit, binit, binit, binit};
            mfma16(w, xh, acc);

            // (5) carry state
            #pragma unroll
            for (int mt = 0; mt < 4; ++mt) accP[mt] = acc[mt];
            p_w2q = w2q; p_wpq = wpq; p_wgq = wgq;
            p_b2v = b2v; p_ppar = ppar;
            #pragma unroll
            for (int mt = 0; mt < 4; ++mt) { p_par[mt] = par[mt]; p_gp[mt] = gp[mt]; }
            p_slot = slot; p_nl = nl;
            havePrev = true;
        }
        // drain
        if (havePrev) {
            const float sv = epilogue_score(accP, p_w2q, p_wpq, p_wgq, p_par, p_gp, p_b2v, quad);
            scW[p_nl][l] = sv;
            const float p = 1.0f / (1.0f + __expf(-sv));
            pp[p_slot][l]        = p_ppar * p;
            pp[p_slot + half][l] = p_ppar * (1.0f - p);
        }
        __syncthreads();
    }

    // ---------------- depth 7: pipelined, fold leaf mixture into VGPRs ----------------
    float oacc[NC];
    #pragma unroll
    for (int c = 0; c < NC; ++c) oacc[c] = 0.0f;
    {
        float (*scP)[TS]  = (float(*)[TS])&scbuf[wbase[0]][0];   // d=6 scores
        float (*scP2)[TS] = (float(*)[TS])&scbuf[wbase[2]][0];   // d=5 scores

        bool havePrev = false;
        f32x4 accP[4];
        float4 p_w2q, p_wpq, p_wgq;
        float  p_b2v = 0.f, p_ppar = 0.f;
        float  p_par[4], p_gp[4];
        int    p_nl = 0;

        for (int nl = wv; nl < 128; nl += 4) {
            const int n = 127 + nl;

            f16x8 w[4];
            loadW(wfrag, n, l, w);
            const float4 b1q = ((const float4*)(b1 + n * 16))[quad];

            if (havePrev) {
                const float sv = epilogue_score(accP, p_w2q, p_wpq, p_wgq, p_par, p_gp, p_b2v, quad);
                const float p = 1.0f / (1.0f + __expf(-sv));
                const float pL = p_ppar * p;
                const float pR = p_ppar * (1.0f - p);
                const float* llp = leaf_logits + (size_t)(2 * p_nl) * NC;
                #pragma unroll
                for (int c = 0; c < NC; ++c)
                    oacc[c] = fmaf(pL, llp[c], fmaf(pR, llp[NC + c], oacc[c]));
            }

            const float4 w2q = ((const float4*)(w2 + n * 16))[quad];
            const float4 wpq = ((const float4*)(W1 + (size_t)n * EFF + 128 * 16))[quad];
            const float4 wgq = ((const float4*)(W1 + (size_t)n * EFF + 129 * 16))[quad];
            const float  b2v = b2[n];
            const float  ppar = pp[nl][l];
            float par[4], gp[4];
            #pragma unroll
            for (int mt = 0; mt < 4; ++mt) {
                const int scol = mt * 16 + col;
                par[mt] = scP[nl >> 1][scol];
                gp[mt]  = scP2[nl >> 2][scol];
            }

            f32x4 binit = {b1q.x, b1q.y, b1q.z, b1q.w};
            f32x4 acc[4] = {binit, binit, binit, binit};
            mfma16(w, xh, acc);

            #pragma unroll
            for (int mt = 0; mt < 4; ++mt) accP[mt] = acc[mt];
            p_w2q = w2q; p_wpq = wpq; p_wgq = wgq;
            p_b2v = b2v; p_ppar = ppar;
            #pragma unroll
            for (int mt = 0; mt < 4; ++mt) { p_par[mt] = par[mt]; p_gp[mt] = gp[mt]; }
            p_nl = nl;
            havePrev = true;
        }
        // drain
        if (havePrev) {
            const float sv = epilogue_score(accP, p_w2q, p_wpq, p_wgq, p_par, p_gp, p_b2v, quad);
            const float p = 1.0f / (1.0f + __expf(-sv));
            const float pL = p_ppar * p;
            const float pR = p_ppar * (1.0f - p);
            const float* llp = leaf_logits + (size_t)(2 * p_nl) * NC;
            #pragma unroll
            for (int c = 0; c < NC; ++c)
                oacc[c] = fmaf(pL, llp[c], fmaf(pR, llp[NC + c], oacc[c]));
        }
    }

    // ---------------- cross-wave out reduction through scbuf ----------------
    __syncthreads();
    {
        float* red = &scbuf[0][0];         // 4*64*10 = 2560 floats <= 7168
        #pragma unroll
        for (int c = 0; c < NC; ++c)
            red[(wv * 64 + l) * NC + c] = oacc[c];
    }
    __syncthreads();
    {
        const float* red = &scbuf[0][0];
        for (int i = tid; i < TS * NC; i += BLOCK) {
            float v = red[i] + red[640 + i] + red[1280 + i] + red[1920 + i];
            out[(size_t)s0 * NC + i] = v;
        }
    }
}

} // namespace

extern "C" void kernel_launch(void* const* d_in, const int* in_sizes, int n_in,
                              void* d_out, int out_size, void* d_ws, size_t ws_size,
                              hipStream_t stream) {
    const float* x           = (const float*)d_in[0];
    const float* path_prob   = (const float*)d_in[1];
    const float* W1          = (const float*)d_in[2];
    const float* b1          = (const float*)d_in[3];
    const float* w2          = (const float*)d_in[4];
    const float* b2          = (const float*)d_in[5];
    const float* leaf_logits = (const float*)d_in[6];
    float* out = (float*)d_out;

    const int batch = in_sizes[0] / IN_DIM;                // 32768
    f16x8* wfrag = (f16x8*)d_ws;                           // 255*4*64*16B ~= 1.04 MB

    hipLaunchKernelGGL(prep_w1, dim3(NODES), dim3(256), 0, stream, W1, wfrag);
    hipLaunchKernelGGL(tree_mfma, dim3(batch / TS), dim3(BLOCK), 0, stream,
                       x, path_prob, W1, b1, w2, b2, leaf_logits, wfrag, out);
}

// Round 15
// 136.409 us; speedup vs baseline: 1.2267x; 1.0270x over previous
//
#include <hip/hip_runtime.h>
#include <math.h>

namespace {

typedef __attribute__((ext_vector_type(8))) __fp16 f16x8;
typedef __attribute__((ext_vector_type(4))) float f32x4;

constexpr int IN_DIM = 128;
constexpr int EFF    = 130 * 16;   // W1 node stride (floats)
constexpr int NODES  = 255;
constexpr int TS     = 64;         // samples per block (4 MFMA N-tiles per wave)
constexpr int BLOCK  = 256;
constexpr int NC     = 10;

// ---- prep: W1[:, :128, :] -> MFMA fragment layout, fp16 (single product) ----
// frag element (n, t, lane l, j): W[k = t*32 + (l>>4)*8 + j][hid = l&15]
__global__ __launch_bounds__(256) void prep_w1(const float* __restrict__ W1,
                                               f16x8* __restrict__ wfrag) {
    __shared__ float xs[IN_DIM * 16];      // 8 KB: rows 0..127 of this node
    const int n = blockIdx.x, tid = threadIdx.x;
    const float4* src = (const float4*)(W1 + (size_t)n * EFF);
    ((float4*)xs)[tid]       = src[tid];
    ((float4*)xs)[tid + 256] = src[tid + 256];
    __syncthreads();
    const int l = tid & 63, t = tid >> 6;
    const int k0 = t * 32 + (l >> 4) * 8, hid = l & 15;
    f16x8 hv;
    #pragma unroll
    for (int j = 0; j < 8; ++j)
        hv[j] = (__fp16)xs[(k0 + j) * 16 + hid];   // RNE
    wfrag[(n * 4 + t) * 64 + l] = hv;
}

__device__ __forceinline__ void loadW(const f16x8* __restrict__ wfrag, int n, int l,
                                      f16x8 (&w)[4]) {
    const f16x8* wp = wfrag + (size_t)n * 256 + l;
    #pragma unroll
    for (int t = 0; t < 4; ++t) w[t] = wp[t * 64];
}

__device__ __forceinline__ void mfma16(const f16x8 (&w)[4], const f16x8 (&xh)[4][4],
                                       f32x4 (&acc)[4]) {
    #pragma unroll
    for (int t = 0; t < 4; ++t)
        #pragma unroll
        for (int mt = 0; mt < 4; ++mt)
            acc[mt] = __builtin_amdgcn_mfma_f32_16x16x32_f16(w[t], xh[t][mt], acc[mt], 0, 0, 0);
}

// combine + hid-reduce (3 in-lane adds + 2 shfls per mt) + lane-select
__device__ __forceinline__ float epilogue_score(
    const f32x4 (&acc)[4], const float4& w2q, const float4& wpq, const float4& wgq,
    const float (&par)[4], const float (&gp)[4], float b2v, int quad)
{
    float score01[4];
    #pragma unroll
    for (int mt = 0; mt < 4; ++mt) {
        float ts = 0.0f;
        #pragma unroll
        for (int r = 0; r < 4; ++r) {
            const float wpr = (r == 0) ? wpq.x : (r == 1) ? wpq.y : (r == 2) ? wpq.z : wpq.w;
            const float wgr = (r == 0) ? wgq.x : (r == 1) ? wgq.y : (r == 2) ? wgq.z : wgq.w;
            const float w2r = (r == 0) ? w2q.x : (r == 1) ? w2q.y : (r == 2) ? w2q.z : w2q.w;
            const float h = fmaf(par[mt], wpr, fmaf(gp[mt], wgr, acc[mt][r]));
            ts = fmaf(fmaxf(h, 0.0f), w2r, ts);
        }
        ts += __shfl_xor(ts, 16);
        ts += __shfl_xor(ts, 32);
        score01[mt] = ts;
    }
    const float sa = (quad & 1) ? score01[1] : score01[0];
    const float sb = (quad & 1) ? score01[3] : score01[2];
    return ((quad & 2) ? sb : sa) + b2v;
}

// ---- main fused tree kernel ----
// R15: subtree-ownership barrier elimination. Wave w owns contiguous nodes
// nl in [w*nd/4,(w+1)*nd/4) at every depth d>=2 -> parent, grandparent and
// pp slots [32w,32w+32) are all WAVE-LOCAL for d>=3. Per-depth scbuf regions
// (offset 2^d-1, 127 rows) remove buffer-rotation WAR under wave drift.
// Only 2 depth barriers (after d=0, d=1) + final reduction barrier, vs 8.
// R14's intra-depth software pipeline retained. Arithmetic unchanged.
__global__ __launch_bounds__(BLOCK) __attribute__((amdgpu_waves_per_eu(2, 2)))
void tree_mfma(
    const float* __restrict__ x, const float* __restrict__ path_prob,
    const float* __restrict__ W1, const float* __restrict__ b1,
    const float* __restrict__ w2, const float* __restrict__ b2,
    const float* __restrict__ leaf_logits,
    const f16x8* __restrict__ wfrag,
    float* __restrict__ out)
{
    __shared__ float pp[128][TS];          // 32 KB: path probs, depths 0..6 only
    __shared__ float scbuf[127][TS];       // 31.75 KB: depth-d scores at row (2^d - 1)

    const int tid  = threadIdx.x;
    const int wv   = tid >> 6, l = tid & 63;
    const int quad = l >> 4,   col = l & 15;
    const int s0   = blockIdx.x * TS;

    if (tid < TS) pp[0][tid] = path_prob[s0 + tid];

    // x fragments (fp16): B operand B[k = t*32+quad*8+j][col]
    f16x8 xh[4][4];
    #pragma unroll
    for (int t = 0; t < 4; ++t)
        #pragma unroll
        for (int mt = 0; mt < 4; ++mt) {
            const float* xp = x + (size_t)(s0 + mt * 16 + col) * IN_DIM + t * 32 + quad * 8;
            float4 v0 = ((const float4*)xp)[0];
            float4 v1 = ((const float4*)xp)[1];
            float vv[8] = {v0.x, v0.y, v0.z, v0.w, v1.x, v1.y, v1.z, v1.w};
            f16x8 hv;
            #pragma unroll
            for (int j = 0; j < 8; ++j) hv[j] = (__fp16)vv[j];
            xh[t][mt] = hv;
        }

    // ---------------- depths 0..6: software-pipelined, subtree-owned ----------------
    for (int d = 0; d < 7; ++d) {
        const int nd = 1 << d;
        float (*scW)[TS]  = (float(*)[TS])&scbuf[nd - 1][0];
        float (*scP)[TS]  = (float(*)[TS])&scbuf[(nd >> 1) - 1][0];   // d-1 region (d>=1)
        float (*scP2)[TS] = (float(*)[TS])&scbuf[(nd >> 2) - 1][0];   // d-2 region (d>=2)
        const int stride = 128 >> d, half = 64 >> d;

        int nlo, nhi;
        if (d >= 2) { nlo = wv * (nd >> 2); nhi = nlo + (nd >> 2); }
        else        { nlo = wv; nhi = (wv < nd) ? wv + 1 : wv; }      // d<2: waves 0..nd-1

        bool havePrev = false;
        f32x4 accP[4];
        float4 p_w2q, p_wpq, p_wgq;
        float  p_b2v = 0.f, p_ppar = 0.f;
        float  p_par[4], p_gp[4];
        int    p_slot = 0, p_nl = 0;

        for (int nl = nlo; nl < nhi; ++nl) {
            const int n = nd - 1 + nl;

            // (1) issue this node's W + b1 loads (hidden under prev epilogue)
            f16x8 w[4];
            loadW(wfrag, n, l, w);
            const float4 b1q = ((const float4*)(b1 + n * 16))[quad];

            // (2) overlapped epilogue of previous node
            if (havePrev) {
                const float sv = epilogue_score(accP, p_w2q, p_wpq, p_wgq, p_par, p_gp, p_b2v, quad);
                scW[p_nl][l] = sv;
                const float p = 1.0f / (1.0f + __expf(-sv));
                pp[p_slot][l]        = p_ppar * p;
                pp[p_slot + half][l] = p_ppar * (1.0f - p);
            }

            // (3) this node's epilogue scalars (consumed NEXT iteration)
            const float4 w2q = ((const float4*)(w2 + n * 16))[quad];
            const float4 wpq = ((const float4*)(W1 + (size_t)n * EFF + 128 * 16))[quad];
            const float4 wgq = ((const float4*)(W1 + (size_t)n * EFF + 129 * 16))[quad];
            const float  b2v = b2[n];
            const int    slot = nl * stride;
            const float  ppar = pp[slot][l];
            float par[4], gp[4];
            #pragma unroll
            for (int mt = 0; mt < 4; ++mt) {
                const int scol = mt * 16 + col;
                par[mt] = (d >= 1) ? scP[nl >> 1][scol] : 0.0f;
                gp[mt]  = (d >= 2) ? scP2[nl >> 2][scol] : 0.0f;
            }

            // (4) MFMA into fresh accumulator (bias folded into init)
            f32x4 binit = {b1q.x, b1q.y, b1q.z, b1q.w};
            f32x4 acc[4] = {binit, binit, binit, binit};
            mfma16(w, xh, acc);

            // (5) carry state
            #pragma unroll
            for (int mt = 0; mt < 4; ++mt) accP[mt] = acc[mt];
            p_w2q = w2q; p_wpq = wpq; p_wgq = wgq;
            p_b2v = b2v; p_ppar = ppar;
            #pragma unroll
            for (int mt = 0; mt < 4; ++mt) { p_par[mt] = par[mt]; p_gp[mt] = gp[mt]; }
            p_slot = slot; p_nl = nl;
            havePrev = true;
        }
        // drain
        if (havePrev) {
            const float sv = epilogue_score(accP, p_w2q, p_wpq, p_wgq, p_par, p_gp, p_b2v, quad);
            scW[p_nl][l] = sv;
            const float p = 1.0f / (1.0f + __expf(-sv));
            pp[p_slot][l]        = p_ppar * p;
            pp[p_slot + half][l] = p_ppar * (1.0f - p);
        }
        // only d0/d1 results are read cross-wave (d>=3 reads are wave-local)
        if (d < 2) __syncthreads();
    }

    // ---------------- depth 7: pipelined fold of leaf mixture (wave-local) ----------------
    float oacc[NC];
    #pragma unroll
    for (int c = 0; c < NC; ++c) oacc[c] = 0.0f;
    {
        float (*scP)[TS]  = (float(*)[TS])&scbuf[63][0];   // d=6 scores
        float (*scP2)[TS] = (float(*)[TS])&scbuf[31][0];   // d=5 scores

        bool havePrev = false;
        f32x4 accP[4];
        float4 p_w2q, p_wpq, p_wgq;
        float  p_b2v = 0.f, p_ppar = 0.f;
        float  p_par[4], p_gp[4];
        int    p_nl = 0;

        const int nlo = wv * 32, nhi = nlo + 32;
        for (int nl = nlo; nl < nhi; ++nl) {
            const int n = 127 + nl;

            f16x8 w[4];
            loadW(wfrag, n, l, w);
            const float4 b1q = ((const float4*)(b1 + n * 16))[quad];

            if (havePrev) {
                const float sv = epilogue_score(accP, p_w2q, p_wpq, p_wgq, p_par, p_gp, p_b2v, quad);
                const float p = 1.0f / (1.0f + __expf(-sv));
                const float pL = p_ppar * p;
                const float pR = p_ppar * (1.0f - p);
                const float* llp = leaf_logits + (size_t)(2 * p_nl) * NC;
                #pragma unroll
                for (int c = 0; c < NC; ++c)
                    oacc[c] = fmaf(pL, llp[c], fmaf(pR, llp[NC + c], oacc[c]));
            }

            const float4 w2q = ((const float4*)(w2 + n * 16))[quad];
            const float4 wpq = ((const float4*)(W1 + (size_t)n * EFF + 128 * 16))[quad];
            const float4 wgq = ((const float4*)(W1 + (size_t)n * EFF + 129 * 16))[quad];
            const float  b2v = b2[n];
            const float  ppar = pp[nl][l];
            float par[4], gp[4];
            #pragma unroll
            for (int mt = 0; mt < 4; ++mt) {
                const int scol = mt * 16 + col;
                par[mt] = scP[nl >> 1][scol];
                gp[mt]  = scP2[nl >> 2][scol];
            }

            f32x4 binit = {b1q.x, b1q.y, b1q.z, b1q.w};
            f32x4 acc[4] = {binit, binit, binit, binit};
            mfma16(w, xh, acc);

            #pragma unroll
            for (int mt = 0; mt < 4; ++mt) accP[mt] = acc[mt];
            p_w2q = w2q; p_wpq = wpq; p_wgq = wgq;
            p_b2v = b2v; p_ppar = ppar;
            #pragma unroll
            for (int mt = 0; mt < 4; ++mt) { p_par[mt] = par[mt]; p_gp[mt] = gp[mt]; }
            p_nl = nl;
            havePrev = true;
        }
        // drain
        if (havePrev) {
            const float sv = epilogue_score(accP, p_w2q, p_wpq, p_wgq, p_par, p_gp, p_b2v, quad);
            const float p = 1.0f / (1.0f + __expf(-sv));
            const float pL = p_ppar * p;
            const float pR = p_ppar * (1.0f - p);
            const float* llp = leaf_logits + (size_t)(2 * p_nl) * NC;
            #pragma unroll
            for (int c = 0; c < NC; ++c)
                oacc[c] = fmaf(pL, llp[c], fmaf(pR, llp[NC + c], oacc[c]));
        }
    }

    // ---------------- cross-wave out reduction through scbuf ----------------
    __syncthreads();
    {
        float* red = &scbuf[0][0];         // 4*64*10 = 2560 floats <= 8128
        #pragma unroll
        for (int c = 0; c < NC; ++c)
            red[(wv * 64 + l) * NC + c] = oacc[c];
    }
    __syncthreads();
    {
        const float* red = &scbuf[0][0];
        for (int i = tid; i < TS * NC; i += BLOCK) {
            float v = red[i] + red[640 + i] + red[1280 + i] + red[1920 + i];
            out[(size_t)s0 * NC + i] = v;
        }
    }
}

} // namespace

extern "C" void kernel_launch(void* const* d_in, const int* in_sizes, int n_in,
                              void* d_out, int out_size, void* d_ws, size_t ws_size,
                              hipStream_t stream) {
    const float* x           = (const float*)d_in[0];
    const float* path_prob   = (const float*)d_in[1];
    const float* W1          = (const float*)d_in[2];
    const float* b1          = (const float*)d_in[3];
    const float* w2          = (const float*)d_in[4];
    const float* b2          = (const float*)d_in[5];
    const float* leaf_logits = (const float*)d_in[6];
    float* out = (float*)d_out;

    const int batch = in_sizes[0] / IN_DIM;                // 32768
    f16x8* wfrag = (f16x8*)d_ws;                           // 255*4*64*16B ~= 1.04 MB

    hipLaunchKernelGGL(prep_w1, dim3(NODES), dim3(256), 0, stream, W1, wfrag);
    hipLaunchKernelGGL(tree_mfma, dim3(batch / TS), dim3(BLOCK), 0, stream,
                       x, path_prob, W1, b1, w2, b2, leaf_logits, wfrag, out);
}